// Round 2
// baseline (17793.889 us; speedup 1.0000x reference)
//
#include <hip/hip_runtime.h>
#include <hip/hip_fp16.h>

#define BB 64
#define SS 512
#define DD 1024
#define HH 1024
#define TICKS 515
#define NBLK 256

typedef _Float16 f16;
typedef __attribute__((ext_vector_type(8))) _Float16 f16x8;
typedef __attribute__((ext_vector_type(4))) _Float16 f16x4;
typedef __attribute__((ext_vector_type(4))) float f32x4;

struct GruWS {
  f16 gi0[2][3 * HH][BB];   // input-side gates layer0, [slot][3H][B], biases folded (bih all, bhh r/z)
  f16 gi1[2][3 * HH][BB];   // same for layer1
  f16 h0b[2][BB][HH];       // layer0 hidden (f16 broadcast copy), slot = step&1
  f16 h1b[2][BB][HH];
  float h0fin[BB * HH];     // layer0 final hidden (f32)
  unsigned bar[64];         // [0]: grid barrier counter (own cacheline-ish)
};

__global__ void gru_init(const float* __restrict__ h0, GruWS* __restrict__ ws) {
  int i = blockIdx.x * 256 + threadIdx.x;
  if (i < BB * HH) {
    ws->h0b[1][0][i] = (f16)h0[i];               // slot 1 == state of "step -1"
  } else if (i < 2 * BB * HH) {
    ws->h1b[1][0][i - BB * HH] = (f16)h0[i];
  }
  if (blockIdx.x == 0 && threadIdx.x == 0) {
    __hip_atomic_store(&ws->bar[0], 0u, __ATOMIC_RELAXED, __HIP_MEMORY_SCOPE_AGENT);
  }
}

// Manual grid barrier: monotonic counter, generation = tick+1.
// thread 0: release-fence (wbl2), arrive, spin at MALL, acquire-fence (inv).
__device__ __forceinline__ void gridbar(unsigned* bar, unsigned gen) {
  __syncthreads();
  if (threadIdx.x == 0) {
    __threadfence();   // agent release: prior stores -> MALL-visible
    __hip_atomic_fetch_add(bar, 1u, __ATOMIC_RELAXED, __HIP_MEMORY_SCOPE_AGENT);
    const unsigned target = gen * NBLK;
    while (__hip_atomic_load(bar, __ATOMIC_RELAXED, __HIP_MEMORY_SCOPE_AGENT) < target) {
      __builtin_amdgcn_s_sleep(1);
    }
    __threadfence();   // agent acquire: invalidate L1/L2 so fresh data is read
  }
  __syncthreads();
}

// Computes full-K (1024) M=64 x N=48 MFMA block. Each wave owns K-quarter
// [wave*256, wave*256+256) with B-fragments preloaded in breg[24].
// Cross-wave K-reduction via LDS. Output: acc[3] (r,z,n tiles) for M-slab == wave.
template <bool AF32>
__device__ __forceinline__ void mma_block(const void* Aab, long astride,
                                          const f16x8* breg, float* red,
                                          int lane, int wave, f32x4 acc[3]) {
  const int kgrp = lane >> 4;
  const int l15 = lane & 15;
  const long kbase = (long)wave * 256 + kgrp * 8;

  f32x4 pacc[4][3];
#pragma unroll
  for (int m = 0; m < 4; ++m)
#pragma unroll
    for (int g = 0; g < 3; ++g) pacc[m][g] = (f32x4){0.f, 0.f, 0.f, 0.f};

  if constexpr (AF32) {
    const float* A = (const float*)Aab;
#pragma unroll
    for (int h = 0; h < 2; ++h) {
      float4 buf[4][4][2];
#pragma unroll
      for (int kk = 0; kk < 4; ++kk)
#pragma unroll
        for (int m = 0; m < 4; ++m) {
          const float* p = A + (long)(m * 16 + l15) * astride + kbase + (long)(h * 4 + kk) * 32;
          buf[kk][m][0] = *(const float4*)p;
          buf[kk][m][1] = *(const float4*)(p + 4);
        }
#pragma unroll
      for (int kk = 0; kk < 4; ++kk)
#pragma unroll
        for (int m = 0; m < 4; ++m) {
          float4 v0 = buf[kk][m][0], v1 = buf[kk][m][1];
          f16x8 a;
          a[0] = (f16)v0.x; a[1] = (f16)v0.y; a[2] = (f16)v0.z; a[3] = (f16)v0.w;
          a[4] = (f16)v1.x; a[5] = (f16)v1.y; a[6] = (f16)v1.z; a[7] = (f16)v1.w;
#pragma unroll
          for (int g = 0; g < 3; ++g)
            pacc[m][g] = __builtin_amdgcn_mfma_f32_16x16x32_f16(a, breg[g * 8 + h * 4 + kk], pacc[m][g], 0, 0, 0);
        }
    }
  } else {
    const f16* A = (const f16*)Aab;
    f16x8 areg[8][4];
#pragma unroll
    for (int kk = 0; kk < 8; ++kk)
#pragma unroll
      for (int m = 0; m < 4; ++m)
        areg[kk][m] = *(const f16x8*)(A + (long)(m * 16 + l15) * astride + kbase + (long)kk * 32);
#pragma unroll
    for (int kk = 0; kk < 8; ++kk)
#pragma unroll
      for (int m = 0; m < 4; ++m)
#pragma unroll
        for (int g = 0; g < 3; ++g)
          pacc[m][g] = __builtin_amdgcn_mfma_f32_16x16x32_f16(areg[kk][m], breg[g * 8 + kk], pacc[m][g], 0, 0, 0);
  }

  // cross-wave K reduction (skip diagonal), lane-major => conflict-free b32
#pragma unroll
  for (int m = 0; m < 4; ++m)
    if (m != wave)
#pragma unroll
      for (int g = 0; g < 3; ++g)
#pragma unroll
        for (int r = 0; r < 4; ++r)
          red[(((wave * 4 + m) * 3 + g) * 4 + r) * 64 + lane] = pacc[m][g][r];
  __syncthreads();
#pragma unroll
  for (int g = 0; g < 3; ++g) {
    f32x4 a = pacc[wave][g];
#pragma unroll
    for (int sw = 0; sw < 4; ++sw)
      if (sw != wave)
#pragma unroll
        for (int r = 0; r < 4; ++r)
          a[r] += red[(((sw * 4 + wave) * 3 + g) * 4 + r) * 64 + lane];
    acc[g] = a;
  }
}

__global__ __launch_bounds__(256, 1) void gru_main(
    const float* __restrict__ x, const float* __restrict__ xmask,
    const float* __restrict__ h0in,
    const float* __restrict__ Wih0, const float* __restrict__ Whh0,
    const float* __restrict__ bih0, const float* __restrict__ bhh0,
    const float* __restrict__ Wih1, const float* __restrict__ Whh1,
    const float* __restrict__ bih1, const float* __restrict__ bhh1,
    float* __restrict__ out, GruWS* __restrict__ ws) {
  __shared__ float red[4 * 4 * 3 * 4 * 64];  // 48 KiB K-reduction scratch

  const int wg = blockIdx.x;
  const int grp = wg >> 6;          // 0:L0gi 1:L0gh 2:L1gi 3:L1gh
  const int gidx = wg & 63;
  const int base = gidx * 16;       // this WG's h-column base
  const int tid = threadIdx.x;
  const int lane = tid & 63;
  const int wave = tid >> 6;
  const int l15 = lane & 15;
  const int kgrp = lane >> 4;
  const int colg = base + l15;               // epilogue / B column
  const int b0 = wave * 16 + kgrp * 4;       // epilogue batch base (C-layout)
  unsigned* bar = &ws->bar[0];

  // --- stage this wave's B fragments (W slice, f32 -> f16) into registers ---
  const float* Wsrc = (grp == 0) ? Wih0 : (grp == 1) ? Whh0 : (grp == 2) ? Wih1 : Whh1;
  f16x8 breg[24];
  {
    const long kbase = (long)wave * 256 + kgrp * 8;
#pragma unroll
    for (int g = 0; g < 3; ++g)
#pragma unroll
      for (int kk = 0; kk < 8; ++kk) {
        const float* p = Wsrc + (long)(g * HH + base + l15) * DD + kbase + (long)kk * 32;
        float4 v0 = *(const float4*)p;
        float4 v1 = *(const float4*)(p + 4);
        f16x8 t;
        t[0] = (f16)v0.x; t[1] = (f16)v0.y; t[2] = (f16)v0.z; t[3] = (f16)v0.w;
        t[4] = (f16)v1.x; t[5] = (f16)v1.y; t[6] = (f16)v1.z; t[7] = (f16)v1.w;
        breg[g * 8 + kk] = t;
      }
  }

  if (grp == 0 || grp == 2) {
    // ---------------- gi role: gi = A @ Wih^T + (bih + bhh_{r,z}) ----------------
    const int layer = (grp == 2);
    const float* bih = layer ? bih1 : bih0;
    const float* bhh = layer ? bhh1 : bhh0;
    float bias[3];
#pragma unroll
    for (int g = 0; g < 3; ++g)
      bias[g] = bih[g * HH + colg] + (g < 2 ? bhh[g * HH + colg] : 0.0f);

    for (int tick = 0; tick < TICKS; ++tick) {
      int s = tick - (layer ? 2 : 0);
      if (s >= 0 && s < SS) {
        f32x4 acc[3];
        if (layer == 0)
          mma_block<true>(x + (long)s * DD, (long)SS * DD, breg, red, lane, wave, acc);
        else
          mma_block<false>(&ws->h0b[s & 1][0][0], HH, breg, red, lane, wave, acc);
        f16* gib = layer ? &ws->gi1[s & 1][0][0] : &ws->gi0[s & 1][0][0];
#pragma unroll
        for (int g = 0; g < 3; ++g) {
          f16x4 o;
#pragma unroll
          for (int r = 0; r < 4; ++r) o[r] = (f16)(acc[g][r] + bias[g]);
          *(f16x4*)(gib + (long)(g * HH + colg) * BB + b0) = o;
        }
      }
      gridbar(bar, (unsigned)(tick + 1));
    }
  } else {
    // ---------------- gh role: recurrent step ----------------
    const int layer = (grp == 3);
    const float* bhh = layer ? bhh1 : bhh0;
    const float bhn = bhh[2 * HH + colg];
    float hold[4], osum[4] = {0.f, 0.f, 0.f, 0.f};
#pragma unroll
    for (int r = 0; r < 4; ++r)
      hold[r] = h0in[(long)layer * BB * HH + (long)(b0 + r) * HH + colg];

    for (int tick = 0; tick < TICKS; ++tick) {
      int s = tick - (layer ? 3 : 1);
      if (s >= 0 && s < SS) {
        const f16* hprev = layer ? &ws->h1b[(s + 1) & 1][0][0] : &ws->h0b[(s + 1) & 1][0][0];
        const f16* gib = layer ? &ws->gi1[s & 1][0][0] : &ws->gi0[s & 1][0][0];
        // issue gi/mask loads early (hidden under the GEMM)
        f16x4 gr = *(const f16x4*)(gib + (long)(0 * HH + colg) * BB + b0);
        f16x4 gz = *(const f16x4*)(gib + (long)(1 * HH + colg) * BB + b0);
        f16x4 gn = *(const f16x4*)(gib + (long)(2 * HH + colg) * BB + b0);
        float mv[4];
#pragma unroll
        for (int r = 0; r < 4; ++r) mv[r] = xmask[(long)(b0 + r) * SS + s];

        f32x4 acc[3];
        mma_block<false>(hprev, HH, breg, red, lane, wave, acc);

        f16* hout = layer ? &ws->h1b[s & 1][0][0] : &ws->h0b[s & 1][0][0];
#pragma unroll
        for (int r = 0; r < 4; ++r) {
          float pr = acc[0][r] + (float)gr[r];
          float pz = acc[1][r] + (float)gz[r];
          float ph = acc[2][r] + bhn;          // gh_n + bhh_n
          float rr = 1.0f / (1.0f + __expf(-pr));
          float zz = 1.0f / (1.0f + __expf(-pz));
          float nn = tanhf((float)gn[r] + rr * ph);
          float upd = hold[r] + (1.0f - zz) * (nn - hold[r]);
          if (mv[r] > 0.5f) {
            hold[r] = upd;
            if (layer) osum[r] += upd;
          }
          hout[(long)(b0 + r) * HH + colg] = (f16)hold[r];
        }
        if (s == SS - 1) {
          if (layer == 0) {
#pragma unroll
            for (int r = 0; r < 4; ++r)
              ws->h0fin[(long)(b0 + r) * HH + colg] = hold[r];
          } else {
#pragma unroll
            for (int r = 0; r < 4; ++r)
              out[(long)(b0 + r) * HH + colg] =
                  (osum[r] + hold[r] + ws->h0fin[(long)(b0 + r) * HH + colg]) * (1.0f / 514.0f);
          }
        }
      }
      gridbar(bar, (unsigned)(tick + 1));
    }
  }
}

extern "C" void kernel_launch(void* const* d_in, const int* in_sizes, int n_in,
                              void* d_out, int out_size, void* d_ws, size_t ws_size,
                              hipStream_t stream) {
  const float* x = (const float*)d_in[0];
  const float* xmask = (const float*)d_in[1];
  const float* h0 = (const float*)d_in[2];
  const float* Wih0 = (const float*)d_in[3];
  const float* Whh0 = (const float*)d_in[4];
  const float* bih0 = (const float*)d_in[5];
  const float* bhh0 = (const float*)d_in[6];
  const float* Wih1 = (const float*)d_in[7];
  const float* Whh1 = (const float*)d_in[8];
  const float* bih1 = (const float*)d_in[9];
  const float* bhh1 = (const float*)d_in[10];
  float* out = (float*)d_out;
  GruWS* ws = (GruWS*)d_ws;

  hipLaunchKernelGGL(gru_init, dim3((2 * BB * HH) / 256), dim3(256), 0, stream, h0, ws);
  hipLaunchKernelGGL(gru_main, dim3(NBLK), dim3(256), 0, stream,
                     x, xmask, h0, Wih0, Whh0, bih0, bhh0,
                     Wih1, Whh1, bih1, bhh1, out, ws);
}

// Round 3
// 11945.380 us; speedup vs baseline: 1.4896x; 1.4896x over previous
//
#include <hip/hip_runtime.h>
#include <hip/hip_fp16.h>

#define BB 64
#define SS 512
#define DD 1024
#define HH 1024
#define TICKS 515
#define NBLK 256

typedef _Float16 f16;
typedef unsigned long long u64;
typedef __attribute__((ext_vector_type(8))) _Float16 f16x8;
typedef __attribute__((ext_vector_type(4))) _Float16 f16x4;
typedef __attribute__((ext_vector_type(4))) float f32x4;

struct GruWS {
  f16 gi0[2][3 * HH][BB];   // input-side gates layer0, [slot][3H][B], biases folded (bih all, bhh r/z)
  f16 gi1[2][3 * HH][BB];   // same for layer1
  f16 h0b[2][BB][HH];       // layer0 hidden (f16), slot = step&1
  f16 h1b[2][BB][HH];
  float h0fin[BB * HH];     // layer0 final hidden (f32)
  unsigned bar[64];         // [0]: grid barrier counter
};

// ---- MALL-coherent access helpers (sc0 sc1: bypass L1/L2, no fences) ----
__device__ __forceinline__ f16x8 ld_sys_f16x8(const f16* p) {
  u64 lo = __hip_atomic_load((const u64*)p,     __ATOMIC_RELAXED, __HIP_MEMORY_SCOPE_SYSTEM);
  u64 hi = __hip_atomic_load((const u64*)p + 1, __ATOMIC_RELAXED, __HIP_MEMORY_SCOPE_SYSTEM);
  union { u64 q[2]; f16x8 v; } u; u.q[0] = lo; u.q[1] = hi; return u.v;
}
__device__ __forceinline__ f16x4 ld_sys_f16x4(const f16* p) {
  u64 q = __hip_atomic_load((const u64*)p, __ATOMIC_RELAXED, __HIP_MEMORY_SCOPE_SYSTEM);
  union { u64 q; f16x4 v; } u; u.q = q; return u.v;
}
__device__ __forceinline__ void st_sys_f16(f16* p, f16 v) {
  union { f16 h; unsigned short s; } u; u.h = v;
  __hip_atomic_store((unsigned short*)p, u.s, __ATOMIC_RELAXED, __HIP_MEMORY_SCOPE_SYSTEM);
}
__device__ __forceinline__ void st_sys_f16x4(f16* p, f16x4 v) {
  union { f16x4 v4; u64 q; } u; u.v4 = v;
  __hip_atomic_store((u64*)p, u.q, __ATOMIC_RELAXED, __HIP_MEMORY_SCOPE_SYSTEM);
}
__device__ __forceinline__ void st_sys_f32(float* p, float v) {
  __hip_atomic_store((unsigned*)p, __builtin_bit_cast(unsigned, v),
                     __ATOMIC_RELAXED, __HIP_MEMORY_SCOPE_SYSTEM);
}
__device__ __forceinline__ float ld_sys_f32(const float* p) {
  unsigned r = __hip_atomic_load((const unsigned*)p, __ATOMIC_RELAXED, __HIP_MEMORY_SCOPE_SYSTEM);
  return __builtin_bit_cast(float, r);
}

__global__ void gru_init(const float* __restrict__ h0, GruWS* __restrict__ ws) {
  int i = blockIdx.x * 256 + threadIdx.x;
  if (i < BB * HH) {
    st_sys_f16(&ws->h0b[1][0][i], (f16)h0[i]);   // slot 1 == state of "step -1"
  } else if (i < 2 * BB * HH) {
    st_sys_f16(&ws->h1b[1][0][i - BB * HH], (f16)h0[i]);
  }
  if (blockIdx.x == 0 && threadIdx.x == 0) {
    __hip_atomic_store(&ws->bar[0], 0u, __ATOMIC_RELAXED, __HIP_MEMORY_SCOPE_SYSTEM);
  }
}

// Grid barrier without any cache flush: all shared data moves via sc0sc1
// (MALL-coherent) accesses, so ordering needs only vmcnt-drain + atomic.
__device__ __forceinline__ void sysbar(unsigned* bar, unsigned gen) {
  __syncthreads();
  if (threadIdx.x == 0) {
    asm volatile("s_waitcnt vmcnt(0)" ::: "memory");  // sc1 stores are MALL-visible once retired
    __hip_atomic_fetch_add(bar, 1u, __ATOMIC_RELAXED, __HIP_MEMORY_SCOPE_SYSTEM);
    const unsigned target = gen * NBLK;
    while (__hip_atomic_load(bar, __ATOMIC_RELAXED, __HIP_MEMORY_SCOPE_SYSTEM) < target) {
      __builtin_amdgcn_s_sleep(2);
    }
    asm volatile("" ::: "memory");  // keep subsequent loads below the spin
  }
  __syncthreads();
}

// Computes full-K (1024) M=64 x N=48 MFMA block. Each wave owns K-quarter
// with B-fragments preloaded in breg[24]. Cross-wave K-reduction via LDS.
// AF32: A is f32, normally cached (x input). else: A is f16 via MALL (h state).
template <bool AF32>
__device__ __forceinline__ void mma_block(const void* Aab, long astride,
                                          const f16x8* breg, float* red,
                                          int lane, int wave, f32x4 acc[3]) {
  const int kgrp = lane >> 4;
  const int l15 = lane & 15;
  const long kbase = (long)wave * 256 + kgrp * 8;

  f32x4 pacc[4][3];
#pragma unroll
  for (int m = 0; m < 4; ++m)
#pragma unroll
    for (int g = 0; g < 3; ++g) pacc[m][g] = (f32x4){0.f, 0.f, 0.f, 0.f};

  if constexpr (AF32) {
    const float* A = (const float*)Aab;
#pragma unroll
    for (int h = 0; h < 2; ++h) {
      float4 buf[4][4][2];
#pragma unroll
      for (int kk = 0; kk < 4; ++kk)
#pragma unroll
        for (int m = 0; m < 4; ++m) {
          const float* p = A + (long)(m * 16 + l15) * astride + kbase + (long)(h * 4 + kk) * 32;
          buf[kk][m][0] = *(const float4*)p;
          buf[kk][m][1] = *(const float4*)(p + 4);
        }
#pragma unroll
      for (int kk = 0; kk < 4; ++kk)
#pragma unroll
        for (int m = 0; m < 4; ++m) {
          float4 v0 = buf[kk][m][0], v1 = buf[kk][m][1];
          f16x8 a;
          a[0] = (f16)v0.x; a[1] = (f16)v0.y; a[2] = (f16)v0.z; a[3] = (f16)v0.w;
          a[4] = (f16)v1.x; a[5] = (f16)v1.y; a[6] = (f16)v1.z; a[7] = (f16)v1.w;
#pragma unroll
          for (int g = 0; g < 3; ++g)
            pacc[m][g] = __builtin_amdgcn_mfma_f32_16x16x32_f16(a, breg[g * 8 + h * 4 + kk], pacc[m][g], 0, 0, 0);
        }
    }
  } else {
    const f16* A = (const f16*)Aab;
    f16x8 areg[8][4];
#pragma unroll
    for (int kk = 0; kk < 8; ++kk)
#pragma unroll
      for (int m = 0; m < 4; ++m)
        areg[kk][m] = ld_sys_f16x8(A + (long)(m * 16 + l15) * astride + kbase + (long)kk * 32);
#pragma unroll
    for (int kk = 0; kk < 8; ++kk)
#pragma unroll
      for (int m = 0; m < 4; ++m)
#pragma unroll
        for (int g = 0; g < 3; ++g)
          pacc[m][g] = __builtin_amdgcn_mfma_f32_16x16x32_f16(areg[kk][m], breg[g * 8 + kk], pacc[m][g], 0, 0, 0);
  }

  // cross-wave K reduction (skip diagonal), lane-major => conflict-free b32
#pragma unroll
  for (int m = 0; m < 4; ++m)
    if (m != wave)
#pragma unroll
      for (int g = 0; g < 3; ++g)
#pragma unroll
        for (int r = 0; r < 4; ++r)
          red[(((wave * 4 + m) * 3 + g) * 4 + r) * 64 + lane] = pacc[m][g][r];
  __syncthreads();
#pragma unroll
  for (int g = 0; g < 3; ++g) {
    f32x4 a = pacc[wave][g];
#pragma unroll
    for (int sw = 0; sw < 4; ++sw)
      if (sw != wave)
#pragma unroll
        for (int r = 0; r < 4; ++r)
          a[r] += red[(((sw * 4 + wave) * 3 + g) * 4 + r) * 64 + lane];
    acc[g] = a;
  }
}

__global__ __launch_bounds__(256, 1) void gru_main(
    const float* __restrict__ x, const float* __restrict__ xmask,
    const float* __restrict__ h0in,
    const float* __restrict__ Wih0, const float* __restrict__ Whh0,
    const float* __restrict__ bih0, const float* __restrict__ bhh0,
    const float* __restrict__ Wih1, const float* __restrict__ Whh1,
    const float* __restrict__ bih1, const float* __restrict__ bhh1,
    float* __restrict__ out, GruWS* __restrict__ ws) {
  __shared__ float red[4 * 4 * 3 * 4 * 64];  // 48 KiB K-reduction scratch

  const int wg = blockIdx.x;
  const int grp = wg >> 6;          // 0:L0gi 1:L0gh 2:L1gi 3:L1gh
  const int gidx = wg & 63;
  const int base = gidx * 16;       // this WG's h-column base
  const int tid = threadIdx.x;
  const int lane = tid & 63;
  const int wave = tid >> 6;
  const int l15 = lane & 15;
  const int kgrp = lane >> 4;
  const int colg = base + l15;               // epilogue / B column
  const int b0 = wave * 16 + kgrp * 4;       // epilogue batch base (C-layout)
  unsigned* bar = &ws->bar[0];

  // --- stage this wave's B fragments (W slice, f32 -> f16) into registers ---
  const float* Wsrc = (grp == 0) ? Wih0 : (grp == 1) ? Whh0 : (grp == 2) ? Wih1 : Whh1;
  f16x8 breg[24];
  {
    const long kbase = (long)wave * 256 + kgrp * 8;
#pragma unroll
    for (int g = 0; g < 3; ++g)
#pragma unroll
      for (int kk = 0; kk < 8; ++kk) {
        const float* p = Wsrc + (long)(g * HH + base + l15) * DD + kbase + (long)kk * 32;
        float4 v0 = *(const float4*)p;
        float4 v1 = *(const float4*)(p + 4);
        f16x8 t;
        t[0] = (f16)v0.x; t[1] = (f16)v0.y; t[2] = (f16)v0.z; t[3] = (f16)v0.w;
        t[4] = (f16)v1.x; t[5] = (f16)v1.y; t[6] = (f16)v1.z; t[7] = (f16)v1.w;
        breg[g * 8 + kk] = t;
      }
  }

  if (grp == 0 || grp == 2) {
    // ---------------- gi role: gi = A @ Wih^T + (bih + bhh_{r,z}) ----------------
    const int layer = (grp == 2);
    const float* bih = layer ? bih1 : bih0;
    const float* bhh = layer ? bhh1 : bhh0;
    float bias[3];
#pragma unroll
    for (int g = 0; g < 3; ++g)
      bias[g] = bih[g * HH + colg] + (g < 2 ? bhh[g * HH + colg] : 0.0f);

    for (int tick = 0; tick < TICKS; ++tick) {
      int s = tick - (layer ? 2 : 0);
      if (s >= 0 && s < SS) {
        f32x4 acc[3];
        if (layer == 0)
          mma_block<true>(x + (long)s * DD, (long)SS * DD, breg, red, lane, wave, acc);
        else
          mma_block<false>(&ws->h0b[s & 1][0][0], HH, breg, red, lane, wave, acc);
        f16* gib = layer ? &ws->gi1[s & 1][0][0] : &ws->gi0[s & 1][0][0];
#pragma unroll
        for (int g = 0; g < 3; ++g) {
          f16x4 o;
#pragma unroll
          for (int r = 0; r < 4; ++r) o[r] = (f16)(acc[g][r] + bias[g]);
          st_sys_f16x4(gib + (long)(g * HH + colg) * BB + b0, o);
        }
      }
      sysbar(bar, (unsigned)(tick + 1));
    }
  } else {
    // ---------------- gh role: recurrent step ----------------
    const int layer = (grp == 3);
    const float* bhh = layer ? bhh1 : bhh0;
    const float bhn = bhh[2 * HH + colg];
    float hold[4], osum[4] = {0.f, 0.f, 0.f, 0.f};
#pragma unroll
    for (int r = 0; r < 4; ++r)
      hold[r] = h0in[(long)layer * BB * HH + (long)(b0 + r) * HH + colg];

    for (int tick = 0; tick < TICKS; ++tick) {
      int s = tick - (layer ? 3 : 1);
      if (s >= 0 && s < SS) {
        const f16* hprev = layer ? &ws->h1b[(s + 1) & 1][0][0] : &ws->h0b[(s + 1) & 1][0][0];
        const f16* gib = layer ? &ws->gi1[s & 1][0][0] : &ws->gi0[s & 1][0][0];
        // issue gi/mask loads early (hidden under the GEMM)
        f16x4 gr = ld_sys_f16x4(gib + (long)(0 * HH + colg) * BB + b0);
        f16x4 gz = ld_sys_f16x4(gib + (long)(1 * HH + colg) * BB + b0);
        f16x4 gn = ld_sys_f16x4(gib + (long)(2 * HH + colg) * BB + b0);
        float mv[4];
#pragma unroll
        for (int r = 0; r < 4; ++r) mv[r] = xmask[(long)(b0 + r) * SS + s];

        f32x4 acc[3];
        mma_block<false>(hprev, HH, breg, red, lane, wave, acc);

        f16* hout = layer ? &ws->h1b[s & 1][0][0] : &ws->h0b[s & 1][0][0];
#pragma unroll
        for (int r = 0; r < 4; ++r) {
          float pr = acc[0][r] + (float)gr[r];
          float pz = acc[1][r] + (float)gz[r];
          float ph = acc[2][r] + bhn;          // gh_n + bhh_n
          float rr = 1.0f / (1.0f + __expf(-pr));
          float zz = 1.0f / (1.0f + __expf(-pz));
          float nn = tanhf((float)gn[r] + rr * ph);
          float upd = hold[r] + (1.0f - zz) * (nn - hold[r]);
          if (mv[r] > 0.5f) {
            hold[r] = upd;
            if (layer) osum[r] += upd;
          }
          st_sys_f16(hout + (long)(b0 + r) * HH + colg, (f16)hold[r]);
        }
        if (s == SS - 1) {
          if (layer == 0) {
#pragma unroll
            for (int r = 0; r < 4; ++r)
              st_sys_f32(&ws->h0fin[(long)(b0 + r) * HH + colg], hold[r]);
          } else {
#pragma unroll
            for (int r = 0; r < 4; ++r)
              out[(long)(b0 + r) * HH + colg] =
                  (osum[r] + hold[r] + ld_sys_f32(&ws->h0fin[(long)(b0 + r) * HH + colg])) * (1.0f / 514.0f);
          }
        }
      }
      sysbar(bar, (unsigned)(tick + 1));
    }
  }
}

extern "C" void kernel_launch(void* const* d_in, const int* in_sizes, int n_in,
                              void* d_out, int out_size, void* d_ws, size_t ws_size,
                              hipStream_t stream) {
  const float* x = (const float*)d_in[0];
  const float* xmask = (const float*)d_in[1];
  const float* h0 = (const float*)d_in[2];
  const float* Wih0 = (const float*)d_in[3];
  const float* Whh0 = (const float*)d_in[4];
  const float* bih0 = (const float*)d_in[5];
  const float* bhh0 = (const float*)d_in[6];
  const float* Wih1 = (const float*)d_in[7];
  const float* Whh1 = (const float*)d_in[8];
  const float* bih1 = (const float*)d_in[9];
  const float* bhh1 = (const float*)d_in[10];
  float* out = (float*)d_out;
  GruWS* ws = (GruWS*)d_ws;

  hipLaunchKernelGGL(gru_init, dim3((2 * BB * HH) / 256), dim3(256), 0, stream, h0, ws);
  hipLaunchKernelGGL(gru_main, dim3(NBLK), dim3(256), 0, stream,
                     x, xmask, h0, Wih0, Whh0, bih0, bhh0,
                     Wih1, Whh1, bih1, bhh1, out, ws);
}

// Round 5
// 9967.059 us; speedup vs baseline: 1.7853x; 1.1985x over previous
//
#include <hip/hip_runtime.h>
#include <hip/hip_fp16.h>

#define BB 64
#define SS 512
#define DD 1024
#define HH 1024
#define TICKS 515
#define NBLK 128

typedef _Float16 f16;
typedef unsigned long long u64;
typedef __attribute__((ext_vector_type(8))) _Float16 f16x8;
typedef __attribute__((ext_vector_type(4))) _Float16 f16x4;
typedef __attribute__((ext_vector_type(4))) float f32x4;

struct GruWS {
  unsigned cnt[4 * 8 * 64];    // exact per-(role,tick) ring: slot[r][t&7] at cnt[(r*8+j)*64], 256B apart
  f16 gi0[4][3 * HH][BB];      // [slot][3H][B]
  f16 gi1[4][3 * HH][BB];
  f16 h0b[4][BB][HH];          // [slot][B][H], slot = s & 3
  f16 h1b[4][BB][HH];
};

// ---- MALL-coherent 16B ops (sc0 sc1: bypass L1/L2, MALL is coherence point) ----
__device__ __forceinline__ f16x8 ld_sys_16B(const void* p) {
  f16x8 r;
  asm volatile("global_load_dwordx4 %0, %1, off sc0 sc1" : "=v"(r) : "v"(p) : "memory");
  return r;
}
__device__ __forceinline__ void st_sys_16B(void* p, f16x8 v) {
  asm volatile("global_store_dwordx4 %0, %1, off sc0 sc1" :: "v"(p), "v"(v) : "memory");
}
__device__ __forceinline__ void drain_vm() {
  asm volatile("s_waitcnt vmcnt(0)" ::: "memory");
  __builtin_amdgcn_sched_barrier(0);
}
__device__ __forceinline__ f16x4 ld_sys_f16x4(const f16* p) {
  u64 q = __hip_atomic_load((const u64*)p, __ATOMIC_RELAXED, __HIP_MEMORY_SCOPE_SYSTEM);
  union { u64 q; f16x4 v; } u; u.q = q; return u.v;
}
__device__ __forceinline__ float ld_sys_f16s(const f16* p) {
  unsigned short s = __hip_atomic_load((const unsigned short*)p, __ATOMIC_RELAXED, __HIP_MEMORY_SCOPE_SYSTEM);
  union { unsigned short s; f16 h; } u; u.s = s; return (float)u.h;
}
__device__ __forceinline__ void st_sys_u16(f16* p, f16 v) {
  union { f16 h; unsigned short s; } u; u.h = v;
  __hip_atomic_store((unsigned short*)p, u.s, __ATOMIC_RELAXED, __HIP_MEMORY_SCOPE_SYSTEM);
}

// done(role, tick): ALL 32 blocks of `role` have completed `tick`.
// slot[role][tick&7] is monotone; after every block passes tick t it holds
// 32 * (number of ticks == t mod 8 completed) = 32*(t/8 + 1).
__device__ __forceinline__ void wait_done(unsigned* cnt, int role, int tick) {
  if (tick < 0) return;
  unsigned* c = &cnt[(role * 8 + (tick & 7)) * 64];
  const unsigned tgt = 32u * ((unsigned)tick / 8u + 1u);
  while (__hip_atomic_load(c, __ATOMIC_RELAXED, __HIP_MEMORY_SCOPE_SYSTEM) < tgt)
    __builtin_amdgcn_s_sleep(4);
  asm volatile("" ::: "memory");
}

__global__ void gru_init(const float* __restrict__ h0, GruWS* __restrict__ ws) {
  int i = blockIdx.x * 256 + threadIdx.x;
  if (i < BB * HH) {
    st_sys_u16(&ws->h0b[3][0][i], (f16)h0[i]);           // slot 3 == state of step -1
  } else if (i < 2 * BB * HH) {
    st_sys_u16(&ws->h1b[3][0][i - BB * HH], (f16)h0[i]);
  }
  if (i < 4 * 8) {
    __hip_atomic_store(&ws->cnt[i * 64], 0u, __ATOMIC_RELAXED, __HIP_MEMORY_SCOPE_SYSTEM);
  }
}

// One K-pass (this wave's K-quarter, one nt column-half): 96 MFMA + LDS K-reduce.
__device__ __forceinline__ void mma_pass(const f16x8 areg[8][4], const f16x8* bnt,
                                         float* red, int lane, int wave, f32x4 acc[3]) {
  f32x4 pacc[4][3];
#pragma unroll
  for (int m = 0; m < 4; ++m)
#pragma unroll
    for (int g = 0; g < 3; ++g) pacc[m][g] = (f32x4){0.f, 0.f, 0.f, 0.f};
#pragma unroll
  for (int kk = 0; kk < 8; ++kk)
#pragma unroll
    for (int m = 0; m < 4; ++m)
#pragma unroll
      for (int g = 0; g < 3; ++g)
        pacc[m][g] = __builtin_amdgcn_mfma_f32_16x16x32_f16(areg[kk][m], bnt[g * 8 + kk], pacc[m][g], 0, 0, 0);
  // cross-wave K reduction (skip diagonal), lane-major conflict-free b32
#pragma unroll
  for (int m = 0; m < 4; ++m)
    if (m != wave)
#pragma unroll
      for (int g = 0; g < 3; ++g)
#pragma unroll
        for (int r = 0; r < 4; ++r)
          red[(((wave * 4 + m) * 3 + g) * 4 + r) * 64 + lane] = pacc[m][g][r];
  __syncthreads();
#pragma unroll
  for (int g = 0; g < 3; ++g) {
    f32x4 a = pacc[wave][g];
#pragma unroll
    for (int sw = 0; sw < 4; ++sw)
      if (sw != wave)
#pragma unroll
        for (int r = 0; r < 4; ++r)
          a[r] += red[(((sw * 4 + wave) * 3 + g) * 4 + r) * 64 + lane];
    acc[g] = a;
  }
}

__global__ __launch_bounds__(256, 1) void gru_main(
    const float* __restrict__ x, const float* __restrict__ xmask,
    const float* __restrict__ h0in,
    const float* __restrict__ Wih0, const float* __restrict__ Whh0,
    const float* __restrict__ bih0, const float* __restrict__ bhh0,
    const float* __restrict__ Wih1, const float* __restrict__ Whh1,
    const float* __restrict__ bih1, const float* __restrict__ bhh1,
    float* __restrict__ out, GruWS* __restrict__ ws) {
  __shared__ __align__(16) char ldsbuf[49152];   // 48KB: K-reduce scratch / store-stage tiles
  float* red = (float*)ldsbuf;

  const int bid = blockIdx.x;
  const int grp = bid >> 5;         // 0:L0gi 1:L0gh 2:L1gi 3:L1gh
  const int gidx = bid & 31;
  const int base = gidx * 32;       // 32 output columns per block
  const int tid = threadIdx.x;
  const int lane = tid & 63;
  const int wave = tid >> 6;
  const int l15 = lane & 15;
  const int kgrp = lane >> 4;
  const int b0 = wave * 16 + kgrp * 4;          // C-fragment batch base
  const int kbase0 = wave * 256 + kgrp * 8;     // this lane's K base
  unsigned* cnt = ws->cnt;

  // ---- stage W slice into registers: breg[nt][g][kk], cols base+nt*16+l15 ----
  const float* Wsrc = (grp == 0) ? Wih0 : (grp == 1) ? Whh0 : (grp == 2) ? Wih1 : Whh1;
  f16x8 breg[2][3][8];
#pragma unroll
  for (int nt = 0; nt < 2; ++nt)
#pragma unroll
    for (int g = 0; g < 3; ++g)
#pragma unroll
      for (int kk = 0; kk < 8; ++kk) {
        const float* p = Wsrc + (long)(g * HH + base + nt * 16 + l15) * DD + kbase0 + kk * 32;
        float4 v0 = *(const float4*)p;
        float4 v1 = *(const float4*)(p + 4);
        f16x8 t;
        t[0] = (f16)v0.x; t[1] = (f16)v0.y; t[2] = (f16)v0.z; t[3] = (f16)v0.w;
        t[4] = (f16)v1.x; t[5] = (f16)v1.y; t[6] = (f16)v1.z; t[7] = (f16)v1.w;
        breg[nt][g][kk] = t;
      }

  if (grp == 0 || grp == 2) {
    // ================= gi roles: gi = A @ Wih^T + (bih + bhh_{r,z}) =================
    const int layer = (grp == 2);
    const float* bih = layer ? bih1 : bih0;
    const float* bhh = layer ? bhh1 : bhh0;
    float bias[2][3];
#pragma unroll
    for (int nt = 0; nt < 2; ++nt)
#pragma unroll
      for (int g = 0; g < 3; ++g) {
        int colg = base + nt * 16 + l15;
        bias[nt][g] = bih[g * HH + colg] + (g < 2 ? bhh[g * HH + colg] : 0.0f);
      }

    for (int t = 0; t < TICKS; ++t) {
      const int s = t - (layer ? 2 : 0);
      const bool active = (s >= 0 && s < SS);
      if (tid == 0 && active) {
        if (!layer) {
          wait_done(cnt, 1, t - 3);               // gi0[s&3] old content consumed
        } else {
          wait_done(cnt, 1, t - 1);               // h0[s] ready (role1 tick s+1 = t-1)
          wait_done(cnt, 3, t - 3);               // gi1[s&3] old content consumed
        }
      }
      __syncthreads();  // S0
      if (active) {
        f16x8 areg[8][4];
        if (!layer) {
#pragma unroll
          for (int kk = 0; kk < 8; ++kk)
#pragma unroll
            for (int m = 0; m < 4; ++m) {
              const float* p = x + (long)(m * 16 + l15) * (SS * DD) + (long)s * DD + kbase0 + kk * 32;
              float4 v0 = *(const float4*)p;
              float4 v1 = *(const float4*)(p + 4);
              f16x8 a;
              a[0] = (f16)v0.x; a[1] = (f16)v0.y; a[2] = (f16)v0.z; a[3] = (f16)v0.w;
              a[4] = (f16)v1.x; a[5] = (f16)v1.y; a[6] = (f16)v1.z; a[7] = (f16)v1.w;
              areg[kk][m] = a;
            }
        } else {
          const f16* A = &ws->h0b[s & 3][0][0];
#pragma unroll
          for (int kk = 0; kk < 8; ++kk)
#pragma unroll
            for (int m = 0; m < 4; ++m)
              areg[kk][m] = ld_sys_16B(A + (long)(m * 16 + l15) * HH + kbase0 + kk * 32);
          drain_vm();
        }
        f32x4 accs[2][3];
        mma_pass(areg, &breg[0][0][0], red, lane, wave, accs[0]);
        __syncthreads();  // S2 (WAR on red)
        mma_pass(areg, &breg[1][0][0], red, lane, wave, accs[1]);
        __syncthreads();  // S4 (red dead -> tile alias)

        f16* gt = (f16*)ldsbuf;   // gi tile [96][64]
#pragma unroll
        for (int nt = 0; nt < 2; ++nt)
#pragma unroll
          for (int g = 0; g < 3; ++g) {
            f16x4 o;
#pragma unroll
            for (int r = 0; r < 4; ++r) o[r] = (f16)(accs[nt][g][r] + bias[nt][g]);
            *(f16x4*)(gt + (g * 32 + nt * 16 + l15) * 64 + b0) = o;
          }
        __syncthreads();  // S5
        f16* gib = layer ? &ws->gi1[s & 3][0][0] : &ws->gi0[s & 3][0][0];
#pragma unroll
        for (int rnd = 0; rnd < 3; ++rnd) {
          int idx = rnd * 256 + tid;
          int row = idx >> 3, ch = idx & 7;
          int g = row >> 5, c = row & 31;
          f16x8 v = *(const f16x8*)(gt + row * 64 + ch * 8);
          st_sys_16B(gib + (long)(g * HH + base + c) * BB + ch * 8, v);
        }
      }
      asm volatile("s_waitcnt vmcnt(0)" ::: "memory");
      __syncthreads();  // S6
      if (tid == 0)
        __hip_atomic_fetch_add(&cnt[(grp * 8 + (t & 7)) * 64], 1u,
                               __ATOMIC_RELAXED, __HIP_MEMORY_SCOPE_SYSTEM);
    }
  } else {
    // ================= gh roles: recurrent step =================
    const int layer = (grp == 3);
    const float* bhh = layer ? bhh1 : bhh0;
    float bhn[2], hold[2][4], osum[2][4];
#pragma unroll
    for (int nt = 0; nt < 2; ++nt) {
      bhn[nt] = bhh[2 * HH + base + nt * 16 + l15];
#pragma unroll
      for (int r = 0; r < 4; ++r) {
        hold[nt][r] = h0in[(long)layer * BB * HH + (long)(b0 + r) * HH + base + nt * 16 + l15];
        osum[nt][r] = 0.f;
      }
    }

    for (int t = 0; t < TICKS; ++t) {
      const int s = t - (layer ? 3 : 1);
      const bool active = (s >= 0 && s < SS);
      if (tid == 0 && active) {
        if (!layer) {
          wait_done(cnt, 0, t - 1);    // gi0[s] ready (role0 tick s = t-1)
          wait_done(cnt, 1, t - 1);    // peers' h0[s-1] ready (lockstep)
          wait_done(cnt, 2, t - 3);    // h0b[s&3] old content consumed by L1gi
        } else {
          wait_done(cnt, 2, t - 1);    // gi1[s] ready (role2 tick s+2 = t-1)
          wait_done(cnt, 3, t - 1);    // peers' h1[s-1] ready (lockstep)
        }
      }
      __syncthreads();  // S0
      if (active) {
        const f16* hprev = layer ? &ws->h1b[(s - 1) & 3][0][0] : &ws->h0b[(s - 1) & 3][0][0];
        const f16* gib = layer ? &ws->gi1[s & 3][0][0] : &ws->gi0[s & 3][0][0];
        f16x8 areg[8][4];
#pragma unroll
        for (int kk = 0; kk < 8; ++kk)
#pragma unroll
          for (int m = 0; m < 4; ++m)
            areg[kk][m] = ld_sys_16B(hprev + (long)(m * 16 + l15) * HH + kbase0 + kk * 32);
        f16x4 gfr[2][3];
#pragma unroll
        for (int nt = 0; nt < 2; ++nt)
#pragma unroll
          for (int g = 0; g < 3; ++g)
            gfr[nt][g] = ld_sys_f16x4(gib + (long)(g * HH + base + nt * 16 + l15) * BB + b0);
        float mv[4];
#pragma unroll
        for (int r = 0; r < 4; ++r) mv[r] = xmask[(long)(b0 + r) * SS + s];
        drain_vm();

        f32x4 accs[2][3];
        mma_pass(areg, &breg[0][0][0], red, lane, wave, accs[0]);
        __syncthreads();  // S2
        mma_pass(areg, &breg[1][0][0], red, lane, wave, accs[1]);
        __syncthreads();  // S4

        f16* htile = (f16*)ldsbuf;  // [64][32]
#pragma unroll
        for (int nt = 0; nt < 2; ++nt)
#pragma unroll
          for (int r = 0; r < 4; ++r) {
            float pr = accs[nt][0][r] + (float)gfr[nt][0][r];
            float pz = accs[nt][1][r] + (float)gfr[nt][1][r];
            float ph = accs[nt][2][r] + bhn[nt];
            float rr = 1.0f / (1.0f + __expf(-pr));
            float zz = 1.0f / (1.0f + __expf(-pz));
            float nn = tanhf((float)gfr[nt][2][r] + rr * ph);
            float upd = hold[nt][r] + (1.0f - zz) * (nn - hold[nt][r]);
            if (mv[r] > 0.5f) {
              hold[nt][r] = upd;
              if (layer) osum[nt][r] += upd;
            }
            htile[(b0 + r) * 32 + nt * 16 + l15] = (f16)hold[nt][r];
          }
        __syncthreads();  // S5
        f16* hout = layer ? &ws->h1b[s & 3][0][0] : &ws->h0b[s & 3][0][0];
        {
          int b = tid >> 2, ch = tid & 3;
          f16x8 v = *(const f16x8*)(htile + b * 32 + ch * 8);
          st_sys_16B(hout + (long)b * HH + base + ch * 8, v);
        }
        if (s == SS - 1 && layer) {
#pragma unroll
          for (int nt = 0; nt < 2; ++nt)
#pragma unroll
            for (int r = 0; r < 4; ++r) {
              int colg = base + nt * 16 + l15;
              float h0f = ld_sys_f16s(&ws->h0b[3][b0 + r][colg]);  // h0[511] lives in slot 3
              out[(long)(b0 + r) * HH + colg] =
                  (osum[nt][r] + hold[nt][r] + h0f) * (1.0f / 514.0f);
            }
        }
      }
      asm volatile("s_waitcnt vmcnt(0)" ::: "memory");
      __syncthreads();  // S6
      if (tid == 0)
        __hip_atomic_fetch_add(&cnt[(grp * 8 + (t & 7)) * 64], 1u,
                               __ATOMIC_RELAXED, __HIP_MEMORY_SCOPE_SYSTEM);
    }
  }
}

extern "C" void kernel_launch(void* const* d_in, const int* in_sizes, int n_in,
                              void* d_out, int out_size, void* d_ws, size_t ws_size,
                              hipStream_t stream) {
  const float* x = (const float*)d_in[0];
  const float* xmask = (const float*)d_in[1];
  const float* h0 = (const float*)d_in[2];
  const float* Wih0 = (const float*)d_in[3];
  const float* Whh0 = (const float*)d_in[4];
  const float* bih0 = (const float*)d_in[5];
  const float* bhh0 = (const float*)d_in[6];
  const float* Wih1 = (const float*)d_in[7];
  const float* Whh1 = (const float*)d_in[8];
  const float* bih1 = (const float*)d_in[9];
  const float* bhh1 = (const float*)d_in[10];
  float* out = (float*)d_out;
  GruWS* ws = (GruWS*)d_ws;

  hipLaunchKernelGGL(gru_init, dim3((2 * BB * HH) / 256), dim3(256), 0, stream, h0, ws);
  hipLaunchKernelGGL(gru_main, dim3(NBLK), dim3(256), 0, stream,
                     x, xmask, h0, Wih0, Whh0, bih0, bhh0,
                     Wih1, Whh1, bih1, bhh1, out, ws);
}